// Round 5
// baseline (176.067 us; speedup 1.0000x reference)
//
#include <hip/hip_runtime.h>
#include <hip/hip_bf16.h>
#include <cstdint>
#include <cstddef>

#define NSRC 100000
#define NDST 50000
#define DOUT 128
#define KK2 256   // 2*D

typedef __attribute__((ext_vector_type(8))) short bf16x8;
typedef __attribute__((ext_vector_type(4))) float f32x4;

static __device__ __forceinline__ unsigned short f2bf(float f) {
    union { float f; uint32_t u; } v; v.f = f;
    uint32_t u = v.u;
    uint32_t r = u + 0x7FFFu + ((u >> 16) & 1u);   // round-to-nearest-even
    return (unsigned short)(r >> 16);
}
static __device__ __forceinline__ float bf_lo(uint32_t u) {
    union { uint32_t x; float f; } v; v.x = u << 16; return v.f;
}
static __device__ __forceinline__ float bf_hi(uint32_t u) {
    union { uint32_t x; float f; } v; v.x = u & 0xFFFF0000u; return v.f;
}

// ---------------- K1: prep — WT bf16 convert + zero counters ----------------
__global__ __launch_bounds__(256) void k_prep(const float* __restrict__ W,
                                              unsigned short* __restrict__ WT,
                                              int* __restrict__ cnt,
                                              int* __restrict__ cnt2) {
    int i = blockIdx.x * 256 + threadIdx.x;
    if (i < DOUT * KK2) {
        int n = i >> 8;    // output col
        int k = i & 255;   // k index
        WT[i] = f2bf(W[k * DOUT + n]);
    }
    if (i < NDST) { cnt[i] = 0; cnt2[i] = 0; }
}

// ---------------- K2: hdelta_bf16 = bf16(H_src - HBar_src), fused dst histogram ----------------
__global__ __launch_bounds__(256) void k_hd_hist(const float4* __restrict__ a,
                                                 const float4* __restrict__ b,
                                                 ushort4* __restrict__ o,
                                                 const int* __restrict__ dst,
                                                 int* __restrict__ cnt,
                                                 int E, int n4) {
    int i = blockIdx.x * 256 + threadIdx.x;
    if (i < E) atomicAdd(&cnt[dst[i]], 1);   // fire-and-forget, hides under streaming
    if (i < n4) {
        float4 x = a[i], y = b[i];
        ushort4 u;
        u.x = f2bf(x.x - y.x); u.y = f2bf(x.y - y.y);
        u.z = f2bf(x.z - y.z); u.w = f2bf(x.w - y.w);
        o[i] = u;
    }
}

// ---------------- K3a: per-block sums ----------------
__global__ __launch_bounds__(256) void k_scan1(const int* __restrict__ cnt,
                                               int* __restrict__ bsum, int n) {
    int i = blockIdx.x * 256 + threadIdx.x;
    int v = (i < n) ? cnt[i] : 0;
#pragma unroll
    for (int s = 1; s < 64; s <<= 1) v += __shfl_xor(v, s, 64);
    __shared__ int wsum[4];
    if ((threadIdx.x & 63) == 0) wsum[threadIdx.x >> 6] = v;
    __syncthreads();
    if (threadIdx.x == 0) bsum[blockIdx.x] = wsum[0] + wsum[1] + wsum[2] + wsum[3];
}

// ---------------- K3b: merged scan — each block derives its own base from bsum,
//                  then scans its 256 cnt values and writes off ----------------
__global__ __launch_bounds__(256) void k_scan23(const int* __restrict__ cnt,
                                                const int* __restrict__ bsum,
                                                int* __restrict__ off,
                                                int n, int nb, int E) {
    __shared__ int wsum[4], wex[4];
    __shared__ int base_s;
    int t = threadIdx.x;
    int lane = t & 63, w = t >> 6;

    // phase A: scan the (nb<=256) block sums; pick out exclusive value at blockIdx.x
    int bv = (t < nb) ? bsum[t] : 0;
    int x = bv;
#pragma unroll
    for (int s = 1; s < 64; s <<= 1) { int tt = __shfl_up(x, s, 64); if (lane >= s) x += tt; }
    if (lane == 63) wsum[w] = x;
    __syncthreads();
    if (t == 0) {
        int run = 0;
#pragma unroll
        for (int k = 0; k < 4; ++k) { wex[k] = run; run += wsum[k]; }
    }
    __syncthreads();
    if (t == (int)blockIdx.x) base_s = wex[w] + x - bv;   // exclusive sum of bsum[0..blockIdx)
    __syncthreads();
    int base = base_s;
    __syncthreads();   // protect wsum/wex reuse

    // phase B: scan this block's cnt slice
    int i = blockIdx.x * 256 + t;
    int v = (i < n) ? cnt[i] : 0;
    x = v;
#pragma unroll
    for (int s = 1; s < 64; s <<= 1) { int tt = __shfl_up(x, s, 64); if (lane >= s) x += tt; }
    if (lane == 63) wsum[w] = x;
    __syncthreads();
    if (t == 0) {
        int run = 0;
#pragma unroll
        for (int k = 0; k < 4; ++k) { wex[k] = run; run += wsum[k]; }
    }
    __syncthreads();
    if (i < n) off[i] = base + wex[w] + x - v;
    if (blockIdx.x == 0 && t == 0) off[n] = E;
}

// ---------------- K4: scatter src ids into dst-sorted buckets ----------------
__global__ void k_scatter(const int* __restrict__ src, const int* __restrict__ dst,
                          const int* __restrict__ off, int* __restrict__ cur,
                          int* __restrict__ idx, int E) {
    int e = blockIdx.x * blockDim.x + threadIdx.x;
    if (e < E) {
        int d = dst[e];
        int p = off[d] + atomicAdd(&cur[d], 1);
        idx[p] = src[e];
    }
}

// ---------------- K5: fused gather-mean-agg + GEMM + bias + relu ----------------
// block = 256 thr = 4 waves, owns 16 dst rows.
// phase 1: wave w gathers rows w*4..w*4+3. Wave splits into two 32-lane halves;
//          each half loads one edge-row per round as uint2 (8 B/lane, 256 B/row),
//          unroll-4 => 8 edges (2 KB) in flight. Cross-half combine via shfl_xor(32).
// phase 2: wave w computes cols [w*32, w*32+32) of the 16x128 output via MFMA.
// LDS row stride 264 shorts (528 B): b128 reads are 2-way bank aliased (free).
__global__ __launch_bounds__(256) void k_fused(const uint2* __restrict__ hd2,
                                               const float4* __restrict__ Hd4,
                                               const float4* __restrict__ agg4,
                                               const int* __restrict__ off,
                                               const int* __restrict__ idx,
                                               const unsigned short* __restrict__ WT,
                                               const float* __restrict__ bias,
                                               float* __restrict__ out) {
    __shared__ __align__(16) unsigned short xt[16][264];
    int r0 = blockIdx.x * 16;
    int w = threadIdx.x >> 6, lane = threadIdx.x & 63;
    int li = lane & 31, half = lane >> 5;

    // ---- phase 1: gather + mean + agg -> LDS x-tile ----
#pragma unroll
    for (int q = 0; q < 4; ++q) {
        int rt = w * 4 + q;
        int r = r0 + rt;
        int o0 = off[r], o1 = off[r + 1];
        float a0 = 0.f, a1 = 0.f, a2 = 0.f, a3 = 0.f;
        int e = o0 + half;                       // this half's first edge
        for (; e + 6 < o1; e += 8) {             // 4 edges per half per round
            int s0 = idx[e], s1 = idx[e + 2], s2 = idx[e + 4], s3 = idx[e + 6];
            uint2 v0 = hd2[(size_t)s0 * 32 + li];
            uint2 v1 = hd2[(size_t)s1 * 32 + li];
            uint2 v2 = hd2[(size_t)s2 * 32 + li];
            uint2 v3 = hd2[(size_t)s3 * 32 + li];
            a0 += bf_lo(v0.x) + bf_lo(v1.x) + bf_lo(v2.x) + bf_lo(v3.x);
            a1 += bf_hi(v0.x) + bf_hi(v1.x) + bf_hi(v2.x) + bf_hi(v3.x);
            a2 += bf_lo(v0.y) + bf_lo(v1.y) + bf_lo(v2.y) + bf_lo(v3.y);
            a3 += bf_hi(v0.y) + bf_hi(v1.y) + bf_hi(v2.y) + bf_hi(v3.y);
        }
        for (; e < o1; e += 2) {
            int s = idx[e];
            uint2 v = hd2[(size_t)s * 32 + li];
            a0 += bf_lo(v.x); a1 += bf_hi(v.x);
            a2 += bf_lo(v.y); a3 += bf_hi(v.y);
        }
        a0 += __shfl_xor(a0, 32); a1 += __shfl_xor(a1, 32);
        a2 += __shfl_xor(a2, 32); a3 += __shfl_xor(a3, 32);
        float inv = 1.0f / fmaxf((float)(o1 - o0), 1.0f);
        if (half == 0) {   // h_neigh half: cols [128+4li, 128+4li+3]
            float4 g = agg4[(size_t)r * 32 + li];
            ushort4 u;
            u.x = f2bf(g.x + a0 * inv); u.y = f2bf(g.y + a1 * inv);
            u.z = f2bf(g.z + a2 * inv); u.w = f2bf(g.w + a3 * inv);
            *(ushort4*)&xt[rt][128 + 4 * li] = u;
        } else {           // H_dst half: cols [4li, 4li+3]
            float4 h = Hd4[(size_t)r * 32 + li];
            ushort4 u;
            u.x = f2bf(h.x); u.y = f2bf(h.y); u.z = f2bf(h.z); u.w = f2bf(h.w);
            *(ushort4*)&xt[rt][4 * li] = u;
        }
    }
    __syncthreads();

    // ---- phase 2: 16x128 GEMM tile, K=256 ----
    int lr = lane & 15, lg = lane >> 4;
    const bf16x8* B0 = reinterpret_cast<const bf16x8*>(WT + (size_t)(w * 32 + lr) * KK2 + lg * 8);
    const bf16x8* B1 = reinterpret_cast<const bf16x8*>(WT + (size_t)(w * 32 + 16 + lr) * KK2 + lg * 8);

    f32x4 acc0 = {0.f, 0.f, 0.f, 0.f};
    f32x4 acc1 = {0.f, 0.f, 0.f, 0.f};
#pragma unroll
    for (int kk = 0; kk < 8; ++kk) {
        bf16x8 av = *reinterpret_cast<const bf16x8*>(&xt[lr][lg * 8 + kk * 32]);
        acc0 = __builtin_amdgcn_mfma_f32_16x16x32_bf16(av, B0[kk * 4], acc0, 0, 0, 0);
        acc1 = __builtin_amdgcn_mfma_f32_16x16x32_bf16(av, B1[kk * 4], acc1, 0, 0, 0);
    }

    int col0 = w * 32 + lr;
    int col1 = col0 + 16;
    float bi0 = bias[col0], bi1 = bias[col1];
    int rowb = r0 + lg * 4;
#pragma unroll
    for (int j = 0; j < 4; ++j) {
        float v0 = acc0[j] + bi0;
        float v1 = acc1[j] + bi1;
        out[(size_t)(rowb + j) * DOUT + col0] = v0 > 0.f ? v0 : 0.f;
        out[(size_t)(rowb + j) * DOUT + col1] = v1 > 0.f ? v1 : 0.f;
    }
}

extern "C" void kernel_launch(void* const* d_in, const int* in_sizes, int n_in,
                              void* d_out, int out_size, void* d_ws, size_t ws_size,
                              hipStream_t stream) {
    const float* H_src    = (const float*)d_in[0];
    const float* H_dst    = (const float*)d_in[1];
    const float* HBar_src = (const float*)d_in[2];
    const float* agg      = (const float*)d_in[3];
    const float* W        = (const float*)d_in[4];
    const float* bias     = (const float*)d_in[5];
    const int*   src      = (const int*)d_in[6];
    const int*   dst      = (const int*)d_in[7];
    float* out = (float*)d_out;
    const int E = in_sizes[6];
    const int NB = (NDST + 255) / 256;   // 196

    // ws layout (byte offsets, 512-aligned):
    //   cnt    : 0         .. 200,000
    //   cnt2   : 200,192   .. 400,192
    //   off    : 400,384   .. 600,388   (NDST+1)
    //   bsum   : 600,576   .. 601,360   (196 i32)
    //   idx    : 602,624   .. 3,802,624 (E i32)
    //   WT     : 3,803,136 .. 3,868,672 (128*256 bf16)
    //   hd_bf  : 3,868,672 .. 29,468,672 (NSRC*128 bf16)
    char* ws = (char*)d_ws;
    int* cnt             = (int*)ws;
    int* cnt2            = (int*)(ws + 200192);
    int* off             = (int*)(ws + 400384);
    int* bsum            = (int*)(ws + 600576);
    int* idx_sorted      = (int*)(ws + 602624);
    unsigned short* WT   = (unsigned short*)(ws + 3803136);
    unsigned short* hdbf = (unsigned short*)(ws + 3868672);

    k_prep<<<NB, 256, 0, stream>>>(W, WT, cnt, cnt2);

    int n4 = NSRC * 32;
    k_hd_hist<<<(n4 + 255) / 256, 256, 0, stream>>>(
        (const float4*)H_src, (const float4*)HBar_src, (ushort4*)hdbf,
        dst, cnt, E, n4);

    k_scan1<<<NB, 256, 0, stream>>>(cnt, bsum, NDST);
    k_scan23<<<NB, 256, 0, stream>>>(cnt, bsum, off, NDST, NB, E);

    k_scatter<<<(E + 255) / 256, 256, 0, stream>>>(src, dst, off, cnt2, idx_sorted, E);

    k_fused<<<NDST / 16, 256, 0, stream>>>(
        (const uint2*)hdbf, (const float4*)H_dst, (const float4*)agg,
        off, idx_sorted, WT, bias, out);
}